// Round 1
// baseline (107274.011 us; speedup 1.0000x reference)
//
#include <hip/hip_runtime.h>
#include <hip/hip_bf16.h>

#define N_EVENTS 50000
#define TS 512
#define NN 256
#define BATCH 512
#define SUB 64
#define LAMB 0.25f

// ---------------- ws layout (float offsets) ----------------
#define OFF_INV   0            // 50000
#define OFF_WCUR  50048        // 131072
#define OFF_CH    181120       // 256
#define OFF_WN2   181376       // 256
#define OFF_RN    181632       // 256
#define OFF_PN    181952       // 256
#define OFF_PHI   182208       // 512
#define OFF_WIN   182720       // 512 (int)
#define OFF_S0    183232       // 512*256
#define OFF_G     314304       // 512*512
// total 576448 floats ~ 2.31 MB

// ---------------- inv norm of each ts row ----------------
__global__ __launch_bounds__(256)
void inv_kernel(const float* __restrict__ ts, float* __restrict__ inv)
{
    __shared__ double red[256];
    const int e = blockIdx.x;
    const int d = threadIdx.x;
    const float* row = ts + (size_t)e * TS;
    float x0 = row[d], x1 = row[d + 256];
    red[d] = (double)x0 * x0 + (double)x1 * x1;
    __syncthreads();
    for (int st = 128; st > 0; st >>= 1) {
        if (d < st) red[d] += red[d + st];
        __syncthreads();
    }
    if (d == 0) inv[e] = (float)(1.0 / sqrt(red[0]));
}

// ---------------- init: ch from input, wn2/rn from W ----------------
__global__ __launch_bounds__(256)
void winit_kernel(const float* __restrict__ Wcur, const float* __restrict__ chin,
                  float* __restrict__ ch, float* __restrict__ wn2, float* __restrict__ rn)
{
    __shared__ double red[256];
    const int n = blockIdx.x;
    const int d = threadIdx.x;
    float w0 = Wcur[n * TS + d], w1 = Wcur[n * TS + d + 256];
    red[d] = (double)w0 * w0 + (double)w1 * w1;
    __syncthreads();
    for (int st = 128; st > 0; st >>= 1) {
        if (d < st) red[d] += red[d + st];
        __syncthreads();
    }
    if (d == 0) {
        double s = red[0];
        wn2[n] = (float)s;
        rn[n]  = (float)(1.0 / sqrt(s));
        ch[n]  = chin[n];
    }
}

// ---------------- S0 = tsn(batch) . W^T   (f64 accumulate) ----------------
__global__ __launch_bounds__(256)
void s0_gemm_kernel(const float* __restrict__ ts, const float* __restrict__ Wcur,
                    const float* __restrict__ inv, float* __restrict__ S0,
                    int bstart, int bs)
{
    __shared__ float At[64][33];
    __shared__ float Bt[64][33];
    const int bf = blockIdx.x;  // 0..7 rows(f)
    const int bn = blockIdx.y;  // 0..3 cols(n)
    if (bf * 64 >= bs) return;
    const int tx = threadIdx.x & 15, ty = threadIdx.x >> 4;
    double acc[4][4] = {};
    for (int kt = 0; kt < TS; kt += 32) {
        for (int it = threadIdx.x; it < 64 * 32; it += 256) {
            int r = it >> 5, c = it & 31;
            int row = bf * 64 + r;
            At[r][c] = (row < bs) ? ts[(size_t)(bstart + row) * TS + kt + c] : 0.f;
            Bt[r][c] = Wcur[(bn * 64 + r) * TS + kt + c];
        }
        __syncthreads();
#pragma unroll
        for (int kk = 0; kk < 32; ++kk) {
            float av[4], bv[4];
#pragma unroll
            for (int i = 0; i < 4; ++i) av[i] = At[ty * 4 + i][kk];
#pragma unroll
            for (int j = 0; j < 4; ++j) bv[j] = Bt[tx * 4 + j][kk];
#pragma unroll
            for (int i = 0; i < 4; ++i)
#pragma unroll
                for (int j = 0; j < 4; ++j)
                    acc[i][j] += (double)av[i] * (double)bv[j];
        }
        __syncthreads();
    }
#pragma unroll
    for (int i = 0; i < 4; ++i) {
        int f = bf * 64 + ty * 4 + i;
        if (f >= bs) continue;
        double iv = (double)inv[bstart + f];
#pragma unroll
        for (int j = 0; j < 4; ++j) {
            int n = bn * 64 + tx * 4 + j;
            S0[f * NN + n] = (float)(acc[i][j] * iv);
        }
    }
}

// ---------------- G[e][f] = tsn_e . tsn_f (upper blocks) ----------------
__global__ __launch_bounds__(256)
void gram_kernel(const float* __restrict__ ts, const float* __restrict__ inv,
                 float* __restrict__ G, int bstart, int bs)
{
    const int be = blockIdx.x, bf = blockIdx.y;
    if (bf < be) return;
    if (be * 64 >= bs || bf * 64 >= bs) return;
    __shared__ float At[64][33];
    __shared__ float Bt[64][33];
    const int tx = threadIdx.x & 15, ty = threadIdx.x >> 4;
    float acc[4][4] = {};
    for (int kt = 0; kt < TS; kt += 32) {
        for (int it = threadIdx.x; it < 64 * 32; it += 256) {
            int r = it >> 5, c = it & 31;
            int re = be * 64 + r, rf = bf * 64 + r;
            At[r][c] = (re < bs) ? ts[(size_t)(bstart + re) * TS + kt + c] : 0.f;
            Bt[r][c] = (rf < bs) ? ts[(size_t)(bstart + rf) * TS + kt + c] : 0.f;
        }
        __syncthreads();
#pragma unroll
        for (int kk = 0; kk < 32; ++kk) {
            float av[4], bv[4];
#pragma unroll
            for (int i = 0; i < 4; ++i) av[i] = At[ty * 4 + i][kk];
#pragma unroll
            for (int j = 0; j < 4; ++j) bv[j] = Bt[tx * 4 + j][kk];
#pragma unroll
            for (int i = 0; i < 4; ++i)
#pragma unroll
                for (int j = 0; j < 4; ++j)
                    acc[i][j] += av[i] * bv[j];
        }
        __syncthreads();
    }
#pragma unroll
    for (int i = 0; i < 4; ++i) {
        int e = be * 64 + ty * 4 + i;
        if (e >= bs) continue;
        float ie = inv[bstart + e];
#pragma unroll
        for (int j = 0; j < 4; ++j) {
            int f = bf * 64 + tx * 4 + j;
            if (f < bs) G[e * BATCH + f] = acc[i][j] * ie * inv[bstart + f];
        }
    }
}

// ---------------- the sequential per-event chain ----------------
__global__ __launch_bounds__(256)
void seq_step_kernel(const float* __restrict__ S0, const float* __restrict__ G,
                     float* __restrict__ ch_g, const float* __restrict__ wn2_g,
                     const float* __restrict__ rn_g, float* __restrict__ Pn_g,
                     float* __restrict__ phi_g, int* __restrict__ win_g,
                     float* __restrict__ winners_out, int bstart, int bs)
{
    __shared__ float ACC[SUB * NN];   // swizzled: phys col = (n + r) & 255
    __shared__ float GS[SUB * SUB];
    __shared__ int   winL[BATCH];
    __shared__ float phiL[BATCH];
    __shared__ float bc[4];

    const int tid = threadIdx.x;
    const int wid = tid >> 6;
    const int lane = tid & 63;

    float ch[4] = {0, 0, 0, 0}, wn2[4] = {1, 1, 1, 1}, rn[4] = {1, 1, 1, 1}, Pn[4] = {1, 1, 1, 1};
    float Ssum = 0.f;
    if (wid == 0) {
#pragma unroll
        for (int k = 0; k < 4; ++k) {
            int n = k * 64 + lane;
            ch[k]  = ch_g[n];
            wn2[k] = wn2_g[n];
            rn[k]  = rn_g[n];
            Pn[k]  = 1.0f;
        }
        // Ssum = sum(ch) : integers, exact in f32
        float loc = ch[0] + ch[1] + ch[2] + ch[3];
#pragma unroll
        for (int off = 32; off > 0; off >>= 1) loc += __shfl_xor(loc, off, 64);
        Ssum = loc;
    }

    const int nsub = (bs + SUB - 1) >> 6;
    for (int sub = 0; sub < nsub; ++sub) {
        const int s0 = sub << 6;
        const int cnt = min(SUB, bs - s0);

        // load S0 rows (swizzled)
        for (int it = tid; it < cnt * NN; it += 256) {
            int r = it >> 8, n = it & 255;
            ACC[r * NN + ((n + r) & 255)] = S0[(s0 + r) * NN + n];
        }
        // load Gsub
        for (int it = tid; it < cnt * SUB; it += 256) {
            int t = it >> 6, f = it & 63;
            GS[t * SUB + f] = (f < cnt) ? G[(s0 + t) * BATCH + (s0 + f)] : 0.f;
        }
        __syncthreads();

        // lazy-apply pending events (columns partitioned across waves)
        for (int e = 0; e < s0; ++e) {
            int w = winL[e];
            if ((w & 3) == wid && lane < cnt) {
                float ph = phiL[e];
                float g = G[e * BATCH + s0 + lane];
                ACC[lane * NN + ((w + lane) & 255)] += ph * g;
            }
        }
        __syncthreads();

        // sequential steps on wave 0
        if (wid == 0) {
            for (int t = 0; t < cnt; ++t) {
                const int ib = s0 + t;
                float a[4], beta[4];
                unsigned long long best = 0ull;
#pragma unroll
                for (int k = 0; k < 4; ++k) {
                    int n = k * 64 + lane;
                    a[k] = ACC[t * NN + ((n + t) & 255)];
                    float dot = Pn[k] * a[k];
                    beta[k] = dot * rn[k];
                    float frac = 256.0f * ch[k] / Ssum;
                    float gain = __expf(LAMB * (1.0f - frac));
                    float key = gain * beta[k];
                    unsigned long long u =
                        ((unsigned long long)__float_as_uint(key) << 32) |
                        (unsigned)(255 - n);
                    best = (u > best) ? u : best;
                }
#pragma unroll
                for (int off = 32; off > 0; off >>= 1) {
                    unsigned long long o = __shfl_xor(best, off, 64);
                    best = (o > best) ? o : best;
                }
                const int ns = 255 - (int)(best & 0xFFull);
                const int owner = ns & 63, ks = ns >> 6;
                if (lane == owner) {
                    float bsel = (ks == 0) ? beta[0] : (ks == 1) ? beta[1] : (ks == 2) ? beta[2] : beta[3];
                    float csel = (ks == 0) ? ch[0]   : (ks == 1) ? ch[1]   : (ks == 2) ? ch[2]   : ch[3];
                    float asel = (ks == 0) ? a[0]    : (ks == 1) ? a[1]    : (ks == 2) ? a[2]    : a[3];
                    float psel = (ks == 0) ? Pn[0]   : (ks == 1) ? Pn[1]   : (ks == 2) ? Pn[2]   : Pn[3];
                    bc[0] = bsel; bc[1] = csel; bc[2] = psel * asel; bc[3] = psel;
                }
                __builtin_amdgcn_wave_barrier();
                float betas = bc[0], chs = bc[1], dots = bc[2], pold = bc[3];
                float alpha = 0.01f / (1.0f + chs / 20000.0f);
                float c = alpha * betas;
                float omc = 1.0f - c;
                float pnew = pold * omc;
                float phi = c / pnew;
#pragma unroll
                for (int k = 0; k < 4; ++k) {
                    if (lane == owner && k == ks) {
                        wn2[k] = omc * omc * wn2[k] + 2.f * c * omc * dots + c * c;
                        rn[k] = 1.0f / sqrtf(wn2[k]);
                        ch[k] += 1.0f;
                        Pn[k] = pnew;
                    }
                }
                Ssum += 1.0f;
                if (lane == 0) {
                    winL[ib] = ns; phiL[ib] = phi;
                    win_g[ib] = ns; phi_g[ib] = phi;
                    winners_out[bstart + ib] = (float)ns;
                }
                int f = t + 1 + lane;
                if (f < cnt)
                    ACC[f * NN + ((ns + f) & 255)] += phi * GS[t * SUB + f];
            }
        }
        __syncthreads();
    }

    if (wid == 0) {
#pragma unroll
        for (int k = 0; k < 4; ++k) {
            int n = k * 64 + lane;
            ch_g[n] = ch[k];
            Pn_g[n] = Pn[k];
        }
    }
}

// ---------------- materialize W for the batch, recompute wn2/rn ----------------
__global__ __launch_bounds__(256)
void wupdate_kernel(const float* __restrict__ ts, const float* __restrict__ inv,
                    const int* __restrict__ win_g, const float* __restrict__ phi_g,
                    const float* __restrict__ Pn_g, float* __restrict__ Wcur,
                    float* __restrict__ wn2_g, float* __restrict__ rn_g,
                    int bstart, int bs)
{
    __shared__ double red[256];
    const int n = blockIdx.x;
    const int d = threadIdx.x;
    const float Pf = Pn_g[n];
    float w0 = Wcur[n * TS + d];
    float w1 = Wcur[n * TS + d + 256];
    double a0 = 0.0, a1 = 0.0;
    for (int ib = 0; ib < bs; ++ib) {
        if (win_g[ib] == n) {
            double coef = (double)phi_g[ib] * (double)Pf;
            float iv = inv[bstart + ib];
            const float* tr = ts + (size_t)(bstart + ib) * TS;
            a0 += coef * (double)(tr[d] * iv);
            a1 += coef * (double)(tr[d + 256] * iv);
        }
    }
    w0 = (float)((double)Pf * (double)w0 + a0);
    w1 = (float)((double)Pf * (double)w1 + a1);
    Wcur[n * TS + d] = w0;
    Wcur[n * TS + d + 256] = w1;
    red[d] = (double)w0 * w0 + (double)w1 * w1;
    __syncthreads();
    for (int st = 128; st > 0; st >>= 1) {
        if (d < st) red[d] += red[d + st];
        __syncthreads();
    }
    if (d == 0) {
        double s = red[0];
        wn2_g[n] = (float)s;
        rn_g[n]  = (float)(1.0 / sqrt(s));
    }
}

// ---------------- final copy: W and ch into d_out ----------------
__global__ __launch_bounds__(256)
void final_kernel(const float* __restrict__ Wcur, const float* __restrict__ ch,
                  float* __restrict__ out)
{
    int i = blockIdx.x * 256 + threadIdx.x;
    if (i < NN * TS) out[N_EVENTS + i] = Wcur[i];
    else if (i < NN * TS + NN) out[N_EVENTS + i] = ch[i - NN * TS];
}

extern "C" void kernel_launch(void* const* d_in, const int* in_sizes, int n_in,
                              void* d_out, int out_size, void* d_ws, size_t ws_size,
                              hipStream_t stream)
{
    const float* ts   = (const float*)d_in[0];
    const float* W0   = (const float*)d_in[1];
    const float* chin = (const float*)d_in[2];
    float* out = (float*)d_out;
    float* ws  = (float*)d_ws;

    float* inv  = ws + OFF_INV;
    float* Wcur = ws + OFF_WCUR;
    float* ch   = ws + OFF_CH;
    float* wn2  = ws + OFF_WN2;
    float* rn   = ws + OFF_RN;
    float* Pn   = ws + OFF_PN;
    float* phi  = ws + OFF_PHI;
    int*   win  = (int*)(ws + OFF_WIN);
    float* S0   = ws + OFF_S0;
    float* G    = ws + OFF_G;

    hipMemcpyAsync(Wcur, W0, (size_t)NN * TS * sizeof(float),
                   hipMemcpyDeviceToDevice, stream);
    inv_kernel<<<N_EVENTS, 256, 0, stream>>>(ts, inv);
    winit_kernel<<<NN, 256, 0, stream>>>(Wcur, chin, ch, wn2, rn);

    const int nbatch = (N_EVENTS + BATCH - 1) / BATCH;
    for (int b = 0; b < nbatch; ++b) {
        int bstart = b * BATCH;
        int bs = min(BATCH, N_EVENTS - bstart);
        s0_gemm_kernel<<<dim3(8, 4), 256, 0, stream>>>(ts, Wcur, inv, S0, bstart, bs);
        gram_kernel<<<dim3(8, 8), 256, 0, stream>>>(ts, inv, G, bstart, bs);
        seq_step_kernel<<<1, 256, 0, stream>>>(S0, G, ch, wn2, rn, Pn, phi, win,
                                               out, bstart, bs);
        wupdate_kernel<<<NN, 256, 0, stream>>>(ts, inv, win, phi, Pn, Wcur,
                                               wn2, rn, bstart, bs);
    }
    final_kernel<<<(NN * TS + NN + 255) / 256, 256, 0, stream>>>(Wcur, ch, out);
}